// Round 5
// baseline (606.192 us; speedup 1.0000x reference)
//
#include <hip/hip_runtime.h>
#include <hip/hip_bf16.h>

typedef __attribute__((ext_vector_type(8))) short short8;
typedef __attribute__((ext_vector_type(4))) float f32x4;

static constexpr int BATCH   = 256;
static constexpr int NIN     = 128;
static constexpr int NH1     = 512;
static constexpr int NH2     = 256;
static constexpr int TC      = 100;
static constexpr int NCHUNK  = 5;

__device__ __forceinline__ unsigned short f2bf(float x) {
    __hip_bfloat16 h = __float2bfloat16(x);
    return *reinterpret_cast<unsigned short*>(&h);
}
__device__ __forceinline__ float bf2f(unsigned short u) {
    __hip_bfloat16 h;
    *reinterpret_cast<unsigned short*>(&h) = u;
    return __bfloat162float(h);
}

__device__ __forceinline__ void gload16(const unsigned short* g, unsigned short* l) {
    __builtin_amdgcn_global_load_lds(
        (const __attribute__((address_space(1))) unsigned int*)(g),
        (__attribute__((address_space(3))) unsigned int*)(l),
        16, 0, 0);
}

// Split f32 weights into 3 exact bf16 components (w = hi+mid+lo, ~24 bits).
// Also zeroes the two atomic spike counters each launch (deterministic).
__global__ __launch_bounds__(256) void prep_weights(
    const float* __restrict__ W1, const float* __restrict__ W2,
    unsigned short* __restrict__ w1s,   // [3][512*128]
    unsigned short* __restrict__ w2s,   // [3][256*512]
    unsigned int* __restrict__ cnt1, unsigned int* __restrict__ cnt2)
{
    int idx = blockIdx.x * 256 + threadIdx.x;
    if (idx == 0) { cnt1[0] = 0u; cnt2[0] = 0u; }
    const int n1 = NH1 * NIN;   // 65536
    const int n2 = NH2 * NH1;   // 131072
    if (idx < n1) {
        float w = W1[idx];
        unsigned short hi = f2bf(w);  float r = w - bf2f(hi);
        unsigned short mi = f2bf(r);  r -= bf2f(mi);
        unsigned short lo = f2bf(r);
        w1s[idx] = hi; w1s[n1 + idx] = mi; w1s[2*n1 + idx] = lo;
    }
    if (idx < n2) {
        float w = W2[idx];
        unsigned short hi = f2bf(w);  float r = w - bf2f(hi);
        unsigned short mi = f2bf(r);  r -= bf2f(mi);
        unsigned short lo = f2bf(r);
        w2s[idx] = hi; w2s[n2 + idx] = mi; w2s[2*n2 + idx] = lo;
    }
}

// GEMM layer 1, fused f32->bf16 A-conversion.
// C[M,512] = spikes_f32[M,128](->bf16) * (Whi+Wmid+Wlo)[512,128]^T + b1
__global__ __launch_bounds__(256) void gemm1_fused(
    const float* __restrict__ A,             // f32 spikes chunk [M,128]
    const unsigned short* __restrict__ Bs,   // [3][512*128] bf16
    const float* __restrict__ bias,
    float* __restrict__ C,
    int M)
{
    constexpr int N = NH1, K = NIN;
    __shared__ __align__(16) unsigned short As[128 * 32];        // 8 KB
    __shared__ __align__(16) unsigned short Bsh[3 * 128 * 32];   // 24 KB

    const int tid  = threadIdx.x;
    const int w    = tid >> 6;
    const int lane = tid & 63;
    const int lr   = lane & 15;
    const int lk   = lane >> 4;
    const int wr   = w >> 1;
    const int wc   = w & 1;

    const int m0 = blockIdx.x * 128;
    const int n0 = blockIdx.y * 128;
    const size_t NK = (size_t)N * K;

    const int ulog = ((lane & 3) ^ ((lane >> 3) & 3)) * 8;
    const unsigned short* gB[6];
    unsigned short* lB[6];
#pragma unroll
    for (int j = 0; j < 6; ++j) {
        int i = w * 6 + j;
        int s = i >> 3, blk = i & 7;
        int row = blk * 16 + (lane >> 2);
        gB[j] = Bs + (size_t)s * NK + (size_t)(n0 + row) * K + ulog;
        lB[j] = &Bsh[s * 4096 + blk * 16 * 32];
    }
    int arow[2], au[2];
    const float* gA[2];
#pragma unroll
    for (int j = 0; j < 2; ++j) {
        int i = tid + j * 256;
        arow[j] = i >> 2; au[j] = i & 3;
        gA[j] = A + (size_t)(m0 + arow[j]) * K + au[j] * 8;
    }

    f32x4 acc[4][4];
#pragma unroll
    for (int i = 0; i < 4; ++i)
#pragma unroll
        for (int j = 0; j < 4; ++j) acc[i][j] = (f32x4){0.f, 0.f, 0.f, 0.f};

#pragma unroll
    for (int ks = 0; ks < 4; ++ks) {
        const int k0 = ks * 32;
#pragma unroll
        for (int j = 0; j < 6; ++j) gload16(gB[j] + k0, lB[j]);
#pragma unroll
        for (int j = 0; j < 2; ++j) {
            float4 va = *reinterpret_cast<const float4*>(gA[j] + k0);
            float4 vb = *reinterpret_cast<const float4*>(gA[j] + k0 + 4);
            short8 u;
            u[0] = (short)f2bf(va.x); u[1] = (short)f2bf(va.y);
            u[2] = (short)f2bf(va.z); u[3] = (short)f2bf(va.w);
            u[4] = (short)f2bf(vb.x); u[5] = (short)f2bf(vb.y);
            u[6] = (short)f2bf(vb.z); u[7] = (short)f2bf(vb.w);
            int pu = au[j] ^ ((arow[j] >> 1) & 3);
            *reinterpret_cast<short8*>(&As[arow[j] * 32 + pu * 8]) = u;
        }
        __syncthreads();

        short8 af[4];
#pragma unroll
        for (int rb = 0; rb < 4; ++rb) {
            int row = wr * 64 + rb * 16 + lr;
            int u = (lk ^ ((row >> 1) & 3)) * 8;
            af[rb] = *reinterpret_cast<const short8*>(&As[row * 32 + u]);
        }
#pragma unroll
        for (int s = 0; s < 3; ++s) {
#pragma unroll
            for (int cb = 0; cb < 4; ++cb) {
                int row = wc * 64 + cb * 16 + lr;
                int u = (lk ^ ((row >> 1) & 3)) * 8;
                short8 bf = *reinterpret_cast<const short8*>(
                    &Bsh[s * 4096 + row * 32 + u]);
#pragma unroll
                for (int rb = 0; rb < 4; ++rb)
                    acc[rb][cb] = __builtin_amdgcn_mfma_f32_16x16x32_bf16(
                        af[rb], bf, acc[rb][cb], 0, 0, 0);
            }
        }
        __syncthreads();
    }

#pragma unroll
    for (int cb = 0; cb < 4; ++cb) {
        int col = n0 + wc * 64 + cb * 16 + lr;
        float bv = bias[col];
#pragma unroll
        for (int rb = 0; rb < 4; ++rb) {
            int row = m0 + wr * 64 + rb * 16 + lk * 4;
#pragma unroll
            for (int j = 0; j < 4; ++j)
                C[(size_t)(row + j) * N + col] = acc[rb][cb][j] + bv;
        }
    }
}

// GEMM layer 2: C[M,256] = spk1_bits[M,512] * (W2 splits)[256,512]^T + b2
// A is bit-packed (1 bit per spike); expand byte->short8 in-register,
// swizzled ds_write_b128 (same both-sides XOR involution as gemm1_fused).
__global__ __launch_bounds__(256) void gemm2(
    const unsigned char* __restrict__ Ab,    // [M*64] bytes (8 k-bits each)
    const unsigned short* __restrict__ Bs,   // [3][256*512]
    const float* __restrict__ bias,
    float* __restrict__ C,
    int M)
{
    constexpr int N = NH2, K = NH1;
    __shared__ __align__(16) unsigned short As[128 * 32];
    __shared__ __align__(16) unsigned short Bsh[3 * 128 * 32];

    const int tid  = threadIdx.x;
    const int w    = tid >> 6;
    const int lane = tid & 63;
    const int lr   = lane & 15;
    const int lk   = lane >> 4;
    const int wr   = w >> 1;
    const int wc   = w & 1;

    const int m0 = blockIdx.x * 128;
    const int n0 = blockIdx.y * 128;
    const size_t NK = (size_t)N * K;

    const int ulog = ((lane & 3) ^ ((lane >> 3) & 3)) * 8;

    int arow[2], au[2];
#pragma unroll
    for (int j = 0; j < 2; ++j) {
        int i = tid + j * 256;
        arow[j] = i >> 2; au[j] = i & 3;
    }
    const unsigned short* gB[6];
    unsigned short* lB[6];
#pragma unroll
    for (int j = 0; j < 6; ++j) {
        int i = w * 6 + j;
        int s = i >> 3, blk = i & 7;
        int row = blk * 16 + (lane >> 2);
        gB[j] = Bs + (size_t)s * NK + (size_t)(n0 + row) * K + ulog;
        lB[j] = &Bsh[s * 4096 + blk * 16 * 32];
    }

    f32x4 acc[4][4];
#pragma unroll
    for (int i = 0; i < 4; ++i)
#pragma unroll
        for (int j = 0; j < 4; ++j) acc[i][j] = (f32x4){0.f, 0.f, 0.f, 0.f};

    for (int k0 = 0; k0 < K; k0 += 32) {
#pragma unroll
        for (int j = 0; j < 6; ++j) gload16(gB[j] + k0, lB[j]);
#pragma unroll
        for (int j = 0; j < 2; ++j) {
            unsigned char bits = Ab[(size_t)(m0 + arow[j]) * 64 + (k0 >> 3) + au[j]];
            short8 u;
#pragma unroll
            for (int b = 0; b < 8; ++b)
                u[b] = ((bits >> b) & 1) ? (short)0x3F80 : (short)0;
            int pu = au[j] ^ ((arow[j] >> 1) & 3);
            *reinterpret_cast<short8*>(&As[arow[j] * 32 + pu * 8]) = u;
        }
        __syncthreads();

        short8 af[4];
#pragma unroll
        for (int rb = 0; rb < 4; ++rb) {
            int row = wr * 64 + rb * 16 + lr;
            int u = (lk ^ ((row >> 1) & 3)) * 8;
            af[rb] = *reinterpret_cast<const short8*>(&As[row * 32 + u]);
        }
#pragma unroll
        for (int s = 0; s < 3; ++s) {
#pragma unroll
            for (int cb = 0; cb < 4; ++cb) {
                int row = wc * 64 + cb * 16 + lr;
                int u = (lk ^ ((row >> 1) & 3)) * 8;
                short8 bf = *reinterpret_cast<const short8*>(
                    &Bsh[s * 4096 + row * 32 + u]);
#pragma unroll
                for (int rb = 0; rb < 4; ++rb)
                    acc[rb][cb] = __builtin_amdgcn_mfma_f32_16x16x32_bf16(
                        af[rb], bf, acc[rb][cb], 0, 0, 0);
            }
        }
        __syncthreads();
    }

#pragma unroll
    for (int cb = 0; cb < 4; ++cb) {
        int col = n0 + wc * 64 + cb * 16 + lr;
        float bv = bias[col];
#pragma unroll
        for (int rb = 0; rb < 4; ++rb) {
            int row = m0 + wr * 64 + rb * 16 + lk * 4;
#pragma unroll
            for (int j = 0; j < 4; ++j)
                C[(size_t)(row + j) * N + col] = acc[rb][cb][j] + bv;
        }
    }
}

// LIF scan layer 1: thread-per-neuron, T unrolled by 4 (4 independent loads
// per iter -> 4x MLP), spikes emitted as ballot bits (1 bit/neuron).
__global__ __launch_bounds__(256) void scan1(
    const float* __restrict__ cur,            // [TC][131072]
    unsigned long long* __restrict__ spkb,    // [TC][2048]
    float* __restrict__ mem_c, float* __restrict__ sum_c,
    unsigned int* __restrict__ cnt_g,
    int first)
{
    int tid = blockIdx.x * 256 + threadIdx.x;  // 131072 threads
    float mem = first ? 0.f : mem_c[tid];
    float sum = first ? 0.f : sum_c[tid];
    float s = (!first && mem > 1.f) ? 1.f : 0.f;   // reset derivable from mem
    int cnt = 0;
    const float beta = 0.8187307530779818f;    // exp(-1/5)
    const int lane = threadIdx.x & 63;
    const int grp = tid >> 6;
    for (int t = 0; t < TC; t += 4) {
        const float* p = cur + (size_t)t * 131072 + tid;
        float c0 = p[0];
        float c1 = p[131072];
        float c2 = p[262144];
        float c3 = p[393216];
        mem = beta * mem + c0 - s; bool b0 = mem > 1.f; s = b0 ? 1.f : 0.f;
        mem = beta * mem + c1 - s; bool b1 = mem > 1.f; s = b1 ? 1.f : 0.f;
        mem = beta * mem + c2 - s; bool b2 = mem > 1.f; s = b2 ? 1.f : 0.f;
        mem = beta * mem + c3 - s; bool b3 = mem > 1.f; s = b3 ? 1.f : 0.f;
        cnt += (int)b0 + (int)b1 + (int)b2 + (int)b3;
        unsigned long long B0 = __ballot(b0);
        unsigned long long B1 = __ballot(b1);
        unsigned long long B2 = __ballot(b2);
        unsigned long long B3 = __ballot(b3);
        if (lane == 0) {
            spkb[(size_t)(t + 0) * 2048 + grp] = B0;
            spkb[(size_t)(t + 1) * 2048 + grp] = B1;
            spkb[(size_t)(t + 2) * 2048 + grp] = B2;
            spkb[(size_t)(t + 3) * 2048 + grp] = B3;
        }
    }
    mem_c[tid] = mem;
    sum_c[tid] = sum + (float)cnt;
    int rc = cnt;
#pragma unroll
    for (int off = 32; off > 0; off >>= 1) rc += __shfl_down(rc, off);
    if (lane == 0) atomicAdd(cnt_g, (unsigned int)rc);
}

// LIF scan layer 2: thread-per-neuron, unroll 4; accumulates mem-sum + count.
__global__ __launch_bounds__(256) void scan2(
    const float* __restrict__ cur,             // [TC][65536]
    float* __restrict__ mem_c, float* __restrict__ msum_c,
    unsigned int* __restrict__ cnt_g,
    int first)
{
    int tid = blockIdx.x * 256 + threadIdx.x;  // 65536 threads
    float mem  = first ? 0.f : mem_c[tid];
    float msum = first ? 0.f : msum_c[tid];
    float s = (!first && mem > 1.f) ? 1.f : 0.f;
    int cnt = 0;
    const float beta = 0.9048374180359595f;    // exp(-1/10)
    for (int t = 0; t < TC; t += 4) {
        const float* p = cur + (size_t)t * 65536 + tid;
        float c0 = p[0];
        float c1 = p[65536];
        float c2 = p[131072];
        float c3 = p[196608];
        mem = beta * mem + c0 - s; msum += mem; bool b0 = mem > 1.f; s = b0 ? 1.f : 0.f;
        mem = beta * mem + c1 - s; msum += mem; bool b1 = mem > 1.f; s = b1 ? 1.f : 0.f;
        mem = beta * mem + c2 - s; msum += mem; bool b2 = mem > 1.f; s = b2 ? 1.f : 0.f;
        mem = beta * mem + c3 - s; msum += mem; bool b3 = mem > 1.f; s = b3 ? 1.f : 0.f;
        cnt += (int)b0 + (int)b1 + (int)b2 + (int)b3;
    }
    mem_c[tid] = mem;
    msum_c[tid] = msum;
    int rc = cnt;
#pragma unroll
    for (int off = 32; off > 0; off >>= 1) rc += __shfl_down(rc, off);
    if ((threadIdx.x & 63) == 0) atomicAdd(cnt_g, (unsigned int)rc);
}

// out[b,o] = (msum[b,:]/T)@Wr[o,:] + br[o] + (s1sum[b,:]/T)@Ws[o,:] + bs[o]
__global__ __launch_bounds__(256) void readout(
    const float* __restrict__ msum, const float* __restrict__ s1sum,
    const float* __restrict__ Wr, const float* __restrict__ br,
    const float* __restrict__ Ws, const float* __restrict__ bs,
    const unsigned int* __restrict__ cnt1, const unsigned int* __restrict__ cnt2,
    float* __restrict__ out)
{
    __shared__ float r0[256], r1[256];
    int b = blockIdx.x, t = threadIdx.x;
    const float inv_t = 1.0f / 500.0f;
    float m  = msum[b * 256 + t] * inv_t;
    float p0 = m * Wr[t];
    float p1 = m * Wr[256 + t];
    float sa = s1sum[b * 512 + t] * inv_t;
    float sb = s1sum[b * 512 + 256 + t] * inv_t;
    p0 += sa * Ws[t]       + sb * Ws[256 + t];
    p1 += sa * Ws[512 + t] + sb * Ws[768 + t];
    r0[t] = p0; r1[t] = p1;
    __syncthreads();
    for (int st = 128; st > 0; st >>= 1) {
        if (t < st) { r0[t] += r0[t + st]; r1[t] += r1[t + st]; }
        __syncthreads();
    }
    if (t == 0) {
        out[b * 2 + 0] = r0[0] + br[0] + bs[0];
        out[b * 2 + 1] = r1[0] + br[1] + bs[1];
        if (b == 0) {
            out[512] = (float)cnt1[0] * (1.0f / 65536000.0f);
            out[513] = (float)cnt2[0] * (1.0f / 32768000.0f);
        }
    }
}

extern "C" void kernel_launch(void* const* d_in, const int* in_sizes, int n_in,
                              void* d_out, int out_size, void* d_ws, size_t ws_size,
                              hipStream_t stream) {
    const float* spikes = (const float*)d_in[0];
    const float* W1 = (const float*)d_in[1];
    const float* b1 = (const float*)d_in[2];
    const float* W2 = (const float*)d_in[3];
    const float* b2 = (const float*)d_in[4];
    const float* Wr = (const float*)d_in[5];
    const float* br = (const float*)d_in[6];
    const float* Ws = (const float*)d_in[7];
    const float* bs = (const float*)d_in[8];
    float* out = (float*)d_out;

    char* wsb = (char*)d_ws;
    size_t o = 0;
    unsigned short* w1s = (unsigned short*)(wsb + o); o += (size_t)3 * 65536 * 2;     // 384 KB
    unsigned short* w2s = (unsigned short*)(wsb + o); o += (size_t)3 * 131072 * 2;    // 768 KB
    float* cur1 = (float*)(wsb + o);                  o += (size_t)TC * 131072 * 4;   // 52.4 MB
    float* cur2 = (float*)(wsb + o);                  o += (size_t)TC * 65536 * 4;    // 26.2 MB
    unsigned long long* spkb = (unsigned long long*)(wsb + o); o += (size_t)TC * 2048 * 8; // 1.64 MB
    float* mem1  = (float*)(wsb + o); o += 524288;
    float* s1sum = (float*)(wsb + o); o += 524288;
    float* mem2  = (float*)(wsb + o); o += 262144;
    float* msum  = (float*)(wsb + o); o += 262144;
    unsigned int* cnt1 = (unsigned int*)(wsb + o); o += 256;
    unsigned int* cnt2 = (unsigned int*)(wsb + o); o += 256;

    prep_weights<<<512, 256, 0, stream>>>(W1, W2, w1s, w2s, cnt1, cnt2);

    const int M = TC * BATCH;   // 25600 rows per chunk
    for (int c = 0; c < NCHUNK; ++c) {
        const float* Ac = spikes + (size_t)c * TC * BATCH * NIN;
        gemm1_fused<<<dim3(M / 128, NH1 / 128), 256, 0, stream>>>(Ac, w1s, b1, cur1, M);
        scan1<<<512, 256, 0, stream>>>(cur1, spkb, mem1, s1sum, cnt1, c == 0);
        gemm2<<<dim3(M / 128, NH2 / 128), 256, 0, stream>>>(
            (const unsigned char*)spkb, w2s, b2, cur2, M);
        scan2<<<256, 256, 0, stream>>>(cur2, mem2, msum, cnt2, c == 0);
    }

    readout<<<256, 256, 0, stream>>>(msum, s1sum, Wr, br, Ws, bs, cnt1, cnt2, out);
}

// Round 6
// 520.527 us; speedup vs baseline: 1.1646x; 1.1646x over previous
//
#include <hip/hip_runtime.h>
#include <hip/hip_bf16.h>

typedef __attribute__((ext_vector_type(8))) short short8;
typedef __attribute__((ext_vector_type(4))) float f32x4;

static constexpr int BATCH   = 256;
static constexpr int NIN     = 128;
static constexpr int NH1     = 512;
static constexpr int NH2     = 256;
static constexpr int TC      = 100;
static constexpr int NCHUNK  = 5;

__device__ __forceinline__ unsigned short f2bf(float x) {
    __hip_bfloat16 h = __float2bfloat16(x);
    return *reinterpret_cast<unsigned short*>(&h);
}
__device__ __forceinline__ float bf2f(unsigned short u) {
    __hip_bfloat16 h;
    *reinterpret_cast<unsigned short*>(&h) = u;
    return __bfloat162float(h);
}

__device__ __forceinline__ void gload16(const unsigned short* g, unsigned short* l) {
    __builtin_amdgcn_global_load_lds(
        (const __attribute__((address_space(1))) unsigned int*)(g),
        (__attribute__((address_space(3))) unsigned int*)(l),
        16, 0, 0);
}

// Split f32 weights into 3 exact bf16 components (w = hi+mid+lo, ~24 bits).
// Also zeroes the two atomic spike counters each launch (deterministic).
__global__ __launch_bounds__(256) void prep_weights(
    const float* __restrict__ W1, const float* __restrict__ W2,
    unsigned short* __restrict__ w1s,   // [3][512*128]
    unsigned short* __restrict__ w2s,   // [3][256*512]
    unsigned int* __restrict__ cnt1, unsigned int* __restrict__ cnt2)
{
    int idx = blockIdx.x * 256 + threadIdx.x;
    if (idx == 0) { cnt1[0] = 0u; cnt2[0] = 0u; }
    const int n1 = NH1 * NIN;   // 65536
    const int n2 = NH2 * NH1;   // 131072
    if (idx < n1) {
        float w = W1[idx];
        unsigned short hi = f2bf(w);  float r = w - bf2f(hi);
        unsigned short mi = f2bf(r);  r -= bf2f(mi);
        unsigned short lo = f2bf(r);
        w1s[idx] = hi; w1s[n1 + idx] = mi; w1s[2*n1 + idx] = lo;
    }
    if (idx < n2) {
        float w = W2[idx];
        unsigned short hi = f2bf(w);  float r = w - bf2f(hi);
        unsigned short mi = f2bf(r);  r -= bf2f(mi);
        unsigned short lo = f2bf(r);
        w2s[idx] = hi; w2s[n2 + idx] = mi; w2s[2*n2 + idx] = lo;
    }
}

// GEMM layer 1, fused f32->bf16 A-conversion.
// C[M,512] = spikes_f32[M,128](->bf16) * (Whi+Wmid+Wlo)[512,128]^T + b1
__global__ __launch_bounds__(256) void gemm1_fused(
    const float* __restrict__ A,             // f32 spikes chunk [M,128]
    const unsigned short* __restrict__ Bs,   // [3][512*128] bf16
    const float* __restrict__ bias,
    float* __restrict__ C,
    int M)
{
    constexpr int N = NH1, K = NIN;
    __shared__ __align__(16) unsigned short As[128 * 32];        // 8 KB
    __shared__ __align__(16) unsigned short Bsh[3 * 128 * 32];   // 24 KB

    const int tid  = threadIdx.x;
    const int w    = tid >> 6;
    const int lane = tid & 63;
    const int lr   = lane & 15;
    const int lk   = lane >> 4;
    const int wr   = w >> 1;
    const int wc   = w & 1;

    const int m0 = blockIdx.x * 128;
    const int n0 = blockIdx.y * 128;
    const size_t NK = (size_t)N * K;

    const int ulog = ((lane & 3) ^ ((lane >> 3) & 3)) * 8;
    const unsigned short* gB[6];
    unsigned short* lB[6];
#pragma unroll
    for (int j = 0; j < 6; ++j) {
        int i = w * 6 + j;
        int s = i >> 3, blk = i & 7;
        int row = blk * 16 + (lane >> 2);
        gB[j] = Bs + (size_t)s * NK + (size_t)(n0 + row) * K + ulog;
        lB[j] = &Bsh[s * 4096 + blk * 16 * 32];
    }
    int arow[2], au[2];
    const float* gA[2];
#pragma unroll
    for (int j = 0; j < 2; ++j) {
        int i = tid + j * 256;
        arow[j] = i >> 2; au[j] = i & 3;
        gA[j] = A + (size_t)(m0 + arow[j]) * K + au[j] * 8;
    }

    f32x4 acc[4][4];
#pragma unroll
    for (int i = 0; i < 4; ++i)
#pragma unroll
        for (int j = 0; j < 4; ++j) acc[i][j] = (f32x4){0.f, 0.f, 0.f, 0.f};

#pragma unroll
    for (int ks = 0; ks < 4; ++ks) {
        const int k0 = ks * 32;
#pragma unroll
        for (int j = 0; j < 6; ++j) gload16(gB[j] + k0, lB[j]);
#pragma unroll
        for (int j = 0; j < 2; ++j) {
            float4 va = *reinterpret_cast<const float4*>(gA[j] + k0);
            float4 vb = *reinterpret_cast<const float4*>(gA[j] + k0 + 4);
            short8 u;
            u[0] = (short)f2bf(va.x); u[1] = (short)f2bf(va.y);
            u[2] = (short)f2bf(va.z); u[3] = (short)f2bf(va.w);
            u[4] = (short)f2bf(vb.x); u[5] = (short)f2bf(vb.y);
            u[6] = (short)f2bf(vb.z); u[7] = (short)f2bf(vb.w);
            int pu = au[j] ^ ((arow[j] >> 1) & 3);
            *reinterpret_cast<short8*>(&As[arow[j] * 32 + pu * 8]) = u;
        }
        __syncthreads();

        short8 af[4];
#pragma unroll
        for (int rb = 0; rb < 4; ++rb) {
            int row = wr * 64 + rb * 16 + lr;
            int u = (lk ^ ((row >> 1) & 3)) * 8;
            af[rb] = *reinterpret_cast<const short8*>(&As[row * 32 + u]);
        }
#pragma unroll
        for (int s = 0; s < 3; ++s) {
#pragma unroll
            for (int cb = 0; cb < 4; ++cb) {
                int row = wc * 64 + cb * 16 + lr;
                int u = (lk ^ ((row >> 1) & 3)) * 8;
                short8 bf = *reinterpret_cast<const short8*>(
                    &Bsh[s * 4096 + row * 32 + u]);
#pragma unroll
                for (int rb = 0; rb < 4; ++rb)
                    acc[rb][cb] = __builtin_amdgcn_mfma_f32_16x16x32_bf16(
                        af[rb], bf, acc[rb][cb], 0, 0, 0);
            }
        }
        __syncthreads();
    }

#pragma unroll
    for (int cb = 0; cb < 4; ++cb) {
        int col = n0 + wc * 64 + cb * 16 + lr;
        float bv = bias[col];
#pragma unroll
        for (int rb = 0; rb < 4; ++rb) {
            int row = m0 + wr * 64 + rb * 16 + lk * 4;
#pragma unroll
            for (int j = 0; j < 4; ++j)
                C[(size_t)(row + j) * N + col] = acc[rb][cb][j] + bv;
        }
    }
}

// GEMM layer 2: C[M,256] = spk1_bits[M,512] * (W2 splits)[256,512]^T + b2
__global__ __launch_bounds__(256) void gemm2(
    const unsigned char* __restrict__ Ab,    // [M*64] bytes (8 k-bits each)
    const unsigned short* __restrict__ Bs,   // [3][256*512]
    const float* __restrict__ bias,
    float* __restrict__ C,
    int M)
{
    constexpr int N = NH2, K = NH1;
    __shared__ __align__(16) unsigned short As[128 * 32];
    __shared__ __align__(16) unsigned short Bsh[3 * 128 * 32];

    const int tid  = threadIdx.x;
    const int w    = tid >> 6;
    const int lane = tid & 63;
    const int lr   = lane & 15;
    const int lk   = lane >> 4;
    const int wr   = w >> 1;
    const int wc   = w & 1;

    const int m0 = blockIdx.x * 128;
    const int n0 = blockIdx.y * 128;
    const size_t NK = (size_t)N * K;

    const int ulog = ((lane & 3) ^ ((lane >> 3) & 3)) * 8;

    int arow[2], au[2];
#pragma unroll
    for (int j = 0; j < 2; ++j) {
        int i = tid + j * 256;
        arow[j] = i >> 2; au[j] = i & 3;
    }
    const unsigned short* gB[6];
    unsigned short* lB[6];
#pragma unroll
    for (int j = 0; j < 6; ++j) {
        int i = w * 6 + j;
        int s = i >> 3, blk = i & 7;
        int row = blk * 16 + (lane >> 2);
        gB[j] = Bs + (size_t)s * NK + (size_t)(n0 + row) * K + ulog;
        lB[j] = &Bsh[s * 4096 + blk * 16 * 32];
    }

    f32x4 acc[4][4];
#pragma unroll
    for (int i = 0; i < 4; ++i)
#pragma unroll
        for (int j = 0; j < 4; ++j) acc[i][j] = (f32x4){0.f, 0.f, 0.f, 0.f};

    for (int k0 = 0; k0 < K; k0 += 32) {
#pragma unroll
        for (int j = 0; j < 6; ++j) gload16(gB[j] + k0, lB[j]);
#pragma unroll
        for (int j = 0; j < 2; ++j) {
            unsigned char bits = Ab[(size_t)(m0 + arow[j]) * 64 + (k0 >> 3) + au[j]];
            short8 u;
#pragma unroll
            for (int b = 0; b < 8; ++b)
                u[b] = ((bits >> b) & 1) ? (short)0x3F80 : (short)0;
            int pu = au[j] ^ ((arow[j] >> 1) & 3);
            *reinterpret_cast<short8*>(&As[arow[j] * 32 + pu * 8]) = u;
        }
        __syncthreads();

        short8 af[4];
#pragma unroll
        for (int rb = 0; rb < 4; ++rb) {
            int row = wr * 64 + rb * 16 + lr;
            int u = (lk ^ ((row >> 1) & 3)) * 8;
            af[rb] = *reinterpret_cast<const short8*>(&As[row * 32 + u]);
        }
#pragma unroll
        for (int s = 0; s < 3; ++s) {
#pragma unroll
            for (int cb = 0; cb < 4; ++cb) {
                int row = wc * 64 + cb * 16 + lr;
                int u = (lk ^ ((row >> 1) & 3)) * 8;
                short8 bf = *reinterpret_cast<const short8*>(
                    &Bsh[s * 4096 + row * 32 + u]);
#pragma unroll
                for (int rb = 0; rb < 4; ++rb)
                    acc[rb][cb] = __builtin_amdgcn_mfma_f32_16x16x32_bf16(
                        af[rb], bf, acc[rb][cb], 0, 0, 0);
            }
        }
        __syncthreads();
    }

#pragma unroll
    for (int cb = 0; cb < 4; ++cb) {
        int col = n0 + wc * 64 + cb * 16 + lr;
        float bv = bias[col];
#pragma unroll
        for (int rb = 0; rb < 4; ++rb) {
            int row = m0 + wr * 64 + rb * 16 + lk * 4;
#pragma unroll
            for (int j = 0; j < 4; ++j)
                C[(size_t)(row + j) * N + col] = acc[rb][cb][j] + bv;
        }
    }
}

// LIF scan layer 1: thread-per-neuron; T=100 as 10 groups of 10,
// software-pipelined (group g+1's 10 loads issued before processing group g)
// -> 2.5KB/wave in flight, loads stream at BW not latency.
__global__ __launch_bounds__(256) void scan1(
    const float* __restrict__ cur,            // [TC][131072]
    unsigned long long* __restrict__ spkb,    // [TC][2048]
    float* __restrict__ mem_c, float* __restrict__ sum_c,
    unsigned int* __restrict__ cnt_g,
    int first)
{
    int tid = blockIdx.x * 256 + threadIdx.x;  // 131072 threads
    float mem = first ? 0.f : mem_c[tid];
    float sum = first ? 0.f : sum_c[tid];
    float s = (!first && mem > 1.f) ? 1.f : 0.f;
    int cnt = 0;
    const float beta = 0.8187307530779818f;    // exp(-1/5)
    const int lane = threadIdx.x & 63;
    const int grp = tid >> 6;
    const float* base = cur + tid;

    float c[10], n[10];
#pragma unroll
    for (int i = 0; i < 10; ++i) c[i] = base[(size_t)i * 131072];

#pragma unroll
    for (int g = 0; g < 10; ++g) {
        if (g < 9) {
#pragma unroll
            for (int i = 0; i < 10; ++i)
                n[i] = base[(size_t)((g + 1) * 10 + i) * 131072];
        }
#pragma unroll
        for (int i = 0; i < 10; ++i) {
            mem = beta * mem + c[i] - s;
            bool b = mem > 1.f;
            s = b ? 1.f : 0.f;
            cnt += (int)b;
            unsigned long long B = __ballot(b);
            if (lane == 0) spkb[(size_t)(g * 10 + i) * 2048 + grp] = B;
        }
#pragma unroll
        for (int i = 0; i < 10; ++i) c[i] = n[i];
    }
    mem_c[tid] = mem;
    sum_c[tid] = sum + (float)cnt;
    int rc = cnt;
#pragma unroll
    for (int off = 32; off > 0; off >>= 1) rc += __shfl_down(rc, off);
    if (lane == 0) atomicAdd(cnt_g, (unsigned int)rc);
}

// LIF scan layer 2: same pipelined structure; accumulates mem-sum + count.
__global__ __launch_bounds__(256) void scan2(
    const float* __restrict__ cur,             // [TC][65536]
    float* __restrict__ mem_c, float* __restrict__ msum_c,
    unsigned int* __restrict__ cnt_g,
    int first)
{
    int tid = blockIdx.x * 256 + threadIdx.x;  // 65536 threads
    float mem  = first ? 0.f : mem_c[tid];
    float msum = first ? 0.f : msum_c[tid];
    float s = (!first && mem > 1.f) ? 1.f : 0.f;
    int cnt = 0;
    const float beta = 0.9048374180359595f;    // exp(-1/10)
    const float* base = cur + tid;

    float c[10], n[10];
#pragma unroll
    for (int i = 0; i < 10; ++i) c[i] = base[(size_t)i * 65536];

#pragma unroll
    for (int g = 0; g < 10; ++g) {
        if (g < 9) {
#pragma unroll
            for (int i = 0; i < 10; ++i)
                n[i] = base[(size_t)((g + 1) * 10 + i) * 65536];
        }
#pragma unroll
        for (int i = 0; i < 10; ++i) {
            mem = beta * mem + c[i] - s;
            msum += mem;
            bool b = mem > 1.f;
            s = b ? 1.f : 0.f;
            cnt += (int)b;
        }
#pragma unroll
        for (int i = 0; i < 10; ++i) c[i] = n[i];
    }
    mem_c[tid] = mem;
    msum_c[tid] = msum;
    int rc = cnt;
#pragma unroll
    for (int off = 32; off > 0; off >>= 1) rc += __shfl_down(rc, off);
    if ((threadIdx.x & 63) == 0) atomicAdd(cnt_g, (unsigned int)rc);
}

// out[b,o] = (msum[b,:]/T)@Wr[o,:] + br[o] + (s1sum[b,:]/T)@Ws[o,:] + bs[o]
__global__ __launch_bounds__(256) void readout(
    const float* __restrict__ msum, const float* __restrict__ s1sum,
    const float* __restrict__ Wr, const float* __restrict__ br,
    const float* __restrict__ Ws, const float* __restrict__ bs,
    const unsigned int* __restrict__ cnt1, const unsigned int* __restrict__ cnt2,
    float* __restrict__ out)
{
    __shared__ float r0[256], r1[256];
    int b = blockIdx.x, t = threadIdx.x;
    const float inv_t = 1.0f / 500.0f;
    float m  = msum[b * 256 + t] * inv_t;
    float p0 = m * Wr[t];
    float p1 = m * Wr[256 + t];
    float sa = s1sum[b * 512 + t] * inv_t;
    float sb = s1sum[b * 512 + 256 + t] * inv_t;
    p0 += sa * Ws[t]       + sb * Ws[256 + t];
    p1 += sa * Ws[512 + t] + sb * Ws[768 + t];
    r0[t] = p0; r1[t] = p1;
    __syncthreads();
    for (int st = 128; st > 0; st >>= 1) {
        if (t < st) { r0[t] += r0[t + st]; r1[t] += r1[t + st]; }
        __syncthreads();
    }
    if (t == 0) {
        out[b * 2 + 0] = r0[0] + br[0] + bs[0];
        out[b * 2 + 1] = r1[0] + br[1] + bs[1];
        if (b == 0) {
            out[512] = (float)cnt1[0] * (1.0f / 65536000.0f);
            out[513] = (float)cnt2[0] * (1.0f / 32768000.0f);
        }
    }
}

extern "C" void kernel_launch(void* const* d_in, const int* in_sizes, int n_in,
                              void* d_out, int out_size, void* d_ws, size_t ws_size,
                              hipStream_t stream) {
    const float* spikes = (const float*)d_in[0];
    const float* W1 = (const float*)d_in[1];
    const float* b1 = (const float*)d_in[2];
    const float* W2 = (const float*)d_in[3];
    const float* b2 = (const float*)d_in[4];
    const float* Wr = (const float*)d_in[5];
    const float* br = (const float*)d_in[6];
    const float* Ws = (const float*)d_in[7];
    const float* bs = (const float*)d_in[8];
    float* out = (float*)d_out;

    char* wsb = (char*)d_ws;
    size_t o = 0;
    unsigned short* w1s = (unsigned short*)(wsb + o); o += (size_t)3 * 65536 * 2;     // 384 KB
    unsigned short* w2s = (unsigned short*)(wsb + o); o += (size_t)3 * 131072 * 2;    // 768 KB
    float* cur1 = (float*)(wsb + o);                  o += (size_t)TC * 131072 * 4;   // 52.4 MB
    float* cur2 = (float*)(wsb + o);                  o += (size_t)TC * 65536 * 4;    // 26.2 MB
    unsigned long long* spkb = (unsigned long long*)(wsb + o); o += (size_t)TC * 2048 * 8; // 1.64 MB
    float* mem1  = (float*)(wsb + o); o += 524288;
    float* s1sum = (float*)(wsb + o); o += 524288;
    float* mem2  = (float*)(wsb + o); o += 262144;
    float* msum  = (float*)(wsb + o); o += 262144;
    unsigned int* cnt1 = (unsigned int*)(wsb + o); o += 256;
    unsigned int* cnt2 = (unsigned int*)(wsb + o); o += 256;

    prep_weights<<<512, 256, 0, stream>>>(W1, W2, w1s, w2s, cnt1, cnt2);

    const int M = TC * BATCH;   // 25600 rows per chunk
    for (int c = 0; c < NCHUNK; ++c) {
        const float* Ac = spikes + (size_t)c * TC * BATCH * NIN;
        gemm1_fused<<<dim3(M / 128, NH1 / 128), 256, 0, stream>>>(Ac, w1s, b1, cur1, M);
        scan1<<<512, 256, 0, stream>>>(cur1, spkb, mem1, s1sum, cnt1, c == 0);
        gemm2<<<dim3(M / 128, NH2 / 128), 256, 0, stream>>>(
            (const unsigned char*)spkb, w2s, b2, cur2, M);
        scan2<<<256, 256, 0, stream>>>(cur2, mem2, msum, cnt2, c == 0);
    }

    readout<<<256, 256, 0, stream>>>(msum, s1sum, Wr, br, Ws, bs, cnt1, cnt2, out);
}

// Round 7
// 383.646 us; speedup vs baseline: 1.5801x; 1.3568x over previous
//
#include <hip/hip_runtime.h>
#include <hip/hip_bf16.h>
#include <hip/hip_fp16.h>

typedef __attribute__((ext_vector_type(8))) short short8;
typedef __attribute__((ext_vector_type(8))) _Float16 f16x8;
typedef __attribute__((ext_vector_type(4))) float f32x4;

static constexpr int BATCH   = 256;
static constexpr int NIN     = 128;
static constexpr int NH1     = 512;
static constexpr int NH2     = 256;
static constexpr int TC      = 250;   // chunk length (2 chunks of 250)
static constexpr int NCHUNK  = 2;
static constexpr float LO_SCALE   = 4096.0f;        // 2^12
static constexpr float LO_INV     = 2.44140625e-4f; // 2^-12

__device__ __forceinline__ unsigned short f2h_bits(float x) {
    _Float16 h = (_Float16)x;
    unsigned short u;
    __builtin_memcpy(&u, &h, 2);
    return u;
}
__device__ __forceinline__ float h2f(unsigned short u) {
    _Float16 h;
    __builtin_memcpy(&h, &u, 2);
    return (float)h;
}

__device__ __forceinline__ void gload16(const unsigned short* g, unsigned short* l) {
    __builtin_amdgcn_global_load_lds(
        (const __attribute__((address_space(1))) unsigned int*)(g),
        (__attribute__((address_space(3))) unsigned int*)(l),
        16, 0, 0);
}

// Split f32 weights into 2 f16 components: w = hi + lo*2^-12 (residual ~|w|*2^-23).
// Also zeroes the two atomic spike counters (deterministic each launch).
__global__ __launch_bounds__(256) void prep_weights(
    const float* __restrict__ W1, const float* __restrict__ W2,
    unsigned short* __restrict__ w1s,   // [2][512*128] f16 bits
    unsigned short* __restrict__ w2s,   // [2][256*512]
    unsigned int* __restrict__ cnt1, unsigned int* __restrict__ cnt2)
{
    int idx = blockIdx.x * 256 + threadIdx.x;
    if (idx == 0) { cnt1[0] = 0u; cnt2[0] = 0u; }
    const int n1 = NH1 * NIN;   // 65536
    const int n2 = NH2 * NH1;   // 131072
    if (idx < n1) {
        float w = W1[idx];
        unsigned short hi = f2h_bits(w);
        float r = (w - h2f(hi)) * LO_SCALE;
        unsigned short lo = f2h_bits(r);
        w1s[idx] = hi; w1s[n1 + idx] = lo;
    }
    if (idx < n2) {
        float w = W2[idx];
        unsigned short hi = f2h_bits(w);
        float r = (w - h2f(hi)) * LO_SCALE;
        unsigned short lo = f2h_bits(r);
        w2s[idx] = hi; w2s[n2 + idx] = lo;
    }
}

// GEMM layer 1: C[M,512] = spikes_f32[M,128](->f16) * (Whi + 2^-12*Wlo)^T + b1
// BM=128 BN=128 BK=32; 4 waves 2x2, wave tile 64x64 (4x4 frags), dual f32 acc.
// A: reg-staged f32->f16 with swizzled ds_write_b128; B: global_load_lds w16,
// source-swizzled (both-sides XOR involution, rule #21).
__global__ __launch_bounds__(256) void gemm1_fused(
    const float* __restrict__ A,             // f32 spikes chunk [M,128]
    const unsigned short* __restrict__ Bs,   // [2][512*128] f16 bits
    const float* __restrict__ bias,
    float* __restrict__ C,
    int M)
{
    constexpr int N = NH1, K = NIN;
    __shared__ __align__(16) unsigned short As[128 * 32];        // 8 KB
    __shared__ __align__(16) unsigned short Bsh[2 * 128 * 32];   // 16 KB

    const int tid  = threadIdx.x;
    const int w    = tid >> 6;
    const int lane = tid & 63;
    const int lr   = lane & 15;
    const int lk   = lane >> 4;
    const int wr   = w >> 1;
    const int wc   = w & 1;

    const int m0 = blockIdx.x * 128;
    const int n0 = blockIdx.y * 128;
    const size_t NK = (size_t)N * K;

    const int ulog = ((lane & 3) ^ ((lane >> 3) & 3)) * 8;
    // B staging: 2 splits x 512 units, 4 per thread
    const unsigned short* gB[4];
    unsigned short* lB[4];
#pragma unroll
    for (int j = 0; j < 4; ++j) {
        int i = w * 4 + j;
        int s = i >> 3, blk = i & 7;
        int row = blk * 16 + (lane >> 2);
        gB[j] = Bs + (size_t)s * NK + (size_t)(n0 + row) * K + ulog;
        lB[j] = &Bsh[s * 4096 + blk * 16 * 32];
    }
    int arow[2], au[2];
    const float* gA[2];
#pragma unroll
    for (int j = 0; j < 2; ++j) {
        int i = tid + j * 256;
        arow[j] = i >> 2; au[j] = i & 3;
        gA[j] = A + (size_t)(m0 + arow[j]) * K + au[j] * 8;
    }

    f32x4 accH[4][4], accL[4][4];
#pragma unroll
    for (int i = 0; i < 4; ++i)
#pragma unroll
        for (int j = 0; j < 4; ++j) {
            accH[i][j] = (f32x4){0.f, 0.f, 0.f, 0.f};
            accL[i][j] = (f32x4){0.f, 0.f, 0.f, 0.f};
        }

#pragma unroll
    for (int ks = 0; ks < 4; ++ks) {
        const int k0 = ks * 32;
#pragma unroll
        for (int j = 0; j < 4; ++j) gload16(gB[j] + k0, lB[j]);
#pragma unroll
        for (int j = 0; j < 2; ++j) {
            float4 va = *reinterpret_cast<const float4*>(gA[j] + k0);
            float4 vb = *reinterpret_cast<const float4*>(gA[j] + k0 + 4);
            short8 u;
            u[0] = (short)f2h_bits(va.x); u[1] = (short)f2h_bits(va.y);
            u[2] = (short)f2h_bits(va.z); u[3] = (short)f2h_bits(va.w);
            u[4] = (short)f2h_bits(vb.x); u[5] = (short)f2h_bits(vb.y);
            u[6] = (short)f2h_bits(vb.z); u[7] = (short)f2h_bits(vb.w);
            int pu = au[j] ^ ((arow[j] >> 1) & 3);
            *reinterpret_cast<short8*>(&As[arow[j] * 32 + pu * 8]) = u;
        }
        __syncthreads();

        f16x8 af[4];
#pragma unroll
        for (int rb = 0; rb < 4; ++rb) {
            int row = wr * 64 + rb * 16 + lr;
            int u = (lk ^ ((row >> 1) & 3)) * 8;
            af[rb] = *reinterpret_cast<const f16x8*>(&As[row * 32 + u]);
        }
#pragma unroll
        for (int cb = 0; cb < 4; ++cb) {
            int row = wc * 64 + cb * 16 + lr;
            int u = (lk ^ ((row >> 1) & 3)) * 8;
            f16x8 bfH = *reinterpret_cast<const f16x8*>(&Bsh[row * 32 + u]);
            f16x8 bfL = *reinterpret_cast<const f16x8*>(&Bsh[4096 + row * 32 + u]);
#pragma unroll
            for (int rb = 0; rb < 4; ++rb) {
                accH[rb][cb] = __builtin_amdgcn_mfma_f32_16x16x32_f16(
                    af[rb], bfH, accH[rb][cb], 0, 0, 0);
                accL[rb][cb] = __builtin_amdgcn_mfma_f32_16x16x32_f16(
                    af[rb], bfL, accL[rb][cb], 0, 0, 0);
            }
        }
        __syncthreads();
    }

#pragma unroll
    for (int cb = 0; cb < 4; ++cb) {
        int col = n0 + wc * 64 + cb * 16 + lr;
        float bv = bias[col];
#pragma unroll
        for (int rb = 0; rb < 4; ++rb) {
            int row = m0 + wr * 64 + rb * 16 + lk * 4;
#pragma unroll
            for (int j = 0; j < 4; ++j)
                C[(size_t)(row + j) * N + col] =
                    fmaf(accL[rb][cb][j], LO_INV, accH[rb][cb][j]) + bv;
        }
    }
}

// GEMM layer 2: C[M,256] = spk1_bits[M,512] * (W2hi + 2^-12*W2lo)^T + b2
// A bit-packed; expand byte -> 8 f16 (0x3C00) in-register, swizzled ds_write.
__global__ __launch_bounds__(256) void gemm2(
    const unsigned char* __restrict__ Ab,    // [M*64] bytes (8 k-bits each)
    const unsigned short* __restrict__ Bs,   // [2][256*512]
    const float* __restrict__ bias,
    float* __restrict__ C,
    int M)
{
    constexpr int N = NH2, K = NH1;
    __shared__ __align__(16) unsigned short As[128 * 32];
    __shared__ __align__(16) unsigned short Bsh[2 * 128 * 32];

    const int tid  = threadIdx.x;
    const int w    = tid >> 6;
    const int lane = tid & 63;
    const int lr   = lane & 15;
    const int lk   = lane >> 4;
    const int wr   = w >> 1;
    const int wc   = w & 1;

    const int m0 = blockIdx.x * 128;
    const int n0 = blockIdx.y * 128;
    const size_t NK = (size_t)N * K;

    const int ulog = ((lane & 3) ^ ((lane >> 3) & 3)) * 8;

    int arow[2], au[2];
#pragma unroll
    for (int j = 0; j < 2; ++j) {
        int i = tid + j * 256;
        arow[j] = i >> 2; au[j] = i & 3;
    }
    const unsigned short* gB[4];
    unsigned short* lB[4];
#pragma unroll
    for (int j = 0; j < 4; ++j) {
        int i = w * 4 + j;
        int s = i >> 3, blk = i & 7;
        int row = blk * 16 + (lane >> 2);
        gB[j] = Bs + (size_t)s * NK + (size_t)(n0 + row) * K + ulog;
        lB[j] = &Bsh[s * 4096 + blk * 16 * 32];
    }

    f32x4 accH[4][4], accL[4][4];
#pragma unroll
    for (int i = 0; i < 4; ++i)
#pragma unroll
        for (int j = 0; j < 4; ++j) {
            accH[i][j] = (f32x4){0.f, 0.f, 0.f, 0.f};
            accL[i][j] = (f32x4){0.f, 0.f, 0.f, 0.f};
        }

    for (int k0 = 0; k0 < K; k0 += 32) {
#pragma unroll
        for (int j = 0; j < 4; ++j) gload16(gB[j] + k0, lB[j]);
#pragma unroll
        for (int j = 0; j < 2; ++j) {
            unsigned char bits = Ab[(size_t)(m0 + arow[j]) * 64 + (k0 >> 3) + au[j]];
            short8 u;
#pragma unroll
            for (int b = 0; b < 8; ++b)
                u[b] = ((bits >> b) & 1) ? (short)0x3C00 : (short)0;   // f16 1.0
            int pu = au[j] ^ ((arow[j] >> 1) & 3);
            *reinterpret_cast<short8*>(&As[arow[j] * 32 + pu * 8]) = u;
        }
        __syncthreads();

        f16x8 af[4];
#pragma unroll
        for (int rb = 0; rb < 4; ++rb) {
            int row = wr * 64 + rb * 16 + lr;
            int u = (lk ^ ((row >> 1) & 3)) * 8;
            af[rb] = *reinterpret_cast<const f16x8*>(&As[row * 32 + u]);
        }
#pragma unroll
        for (int cb = 0; cb < 4; ++cb) {
            int row = wc * 64 + cb * 16 + lr;
            int u = (lk ^ ((row >> 1) & 3)) * 8;
            f16x8 bfH = *reinterpret_cast<const f16x8*>(&Bsh[row * 32 + u]);
            f16x8 bfL = *reinterpret_cast<const f16x8*>(&Bsh[4096 + row * 32 + u]);
#pragma unroll
            for (int rb = 0; rb < 4; ++rb) {
                accH[rb][cb] = __builtin_amdgcn_mfma_f32_16x16x32_f16(
                    af[rb], bfH, accH[rb][cb], 0, 0, 0);
                accL[rb][cb] = __builtin_amdgcn_mfma_f32_16x16x32_f16(
                    af[rb], bfL, accL[rb][cb], 0, 0, 0);
            }
        }
        __syncthreads();
    }

#pragma unroll
    for (int cb = 0; cb < 4; ++cb) {
        int col = n0 + wc * 64 + cb * 16 + lr;
        float bv = bias[col];
#pragma unroll
        for (int rb = 0; rb < 4; ++rb) {
            int row = m0 + wr * 64 + rb * 16 + lk * 4;
#pragma unroll
            for (int j = 0; j < 4; ++j)
                C[(size_t)(row + j) * N + col] =
                    fmaf(accL[rb][cb][j], LO_INV, accH[rb][cb][j]) + bv;
        }
    }
}

// LIF scan layer 1: thread-per-neuron; T=250 as 25 groups of 10,
// software-pipelined (next group's 10 loads issued before processing current).
__global__ __launch_bounds__(256) void scan1(
    const float* __restrict__ cur,            // [TC][131072]
    unsigned long long* __restrict__ spkb,    // [TC][2048]
    float* __restrict__ mem_c, float* __restrict__ sum_c,
    unsigned int* __restrict__ cnt_g,
    int first)
{
    int tid = blockIdx.x * 256 + threadIdx.x;  // 131072 threads
    float mem = first ? 0.f : mem_c[tid];
    float sum = first ? 0.f : sum_c[tid];
    float s = (!first && mem > 1.f) ? 1.f : 0.f;
    int cnt = 0;
    const float beta = 0.8187307530779818f;    // exp(-1/5)
    const int lane = threadIdx.x & 63;
    const int grp = tid >> 6;
    const float* base = cur + tid;

    float c[10], n[10];
#pragma unroll
    for (int i = 0; i < 10; ++i) c[i] = base[(size_t)i * 131072];

#pragma unroll
    for (int g = 0; g < 25; ++g) {
        if (g < 24) {
#pragma unroll
            for (int i = 0; i < 10; ++i)
                n[i] = base[(size_t)((g + 1) * 10 + i) * 131072];
        }
#pragma unroll
        for (int i = 0; i < 10; ++i) {
            mem = beta * mem + c[i] - s;
            bool b = mem > 1.f;
            s = b ? 1.f : 0.f;
            cnt += (int)b;
            unsigned long long B = __ballot(b);
            if (lane == 0) spkb[(size_t)(g * 10 + i) * 2048 + grp] = B;
        }
#pragma unroll
        for (int i = 0; i < 10; ++i) c[i] = n[i];
    }
    mem_c[tid] = mem;
    sum_c[tid] = sum + (float)cnt;
    int rc = cnt;
#pragma unroll
    for (int off = 32; off > 0; off >>= 1) rc += __shfl_down(rc, off);
    if (lane == 0) atomicAdd(cnt_g, (unsigned int)rc);
}

// LIF scan layer 2: same pipelined structure; accumulates mem-sum + count.
__global__ __launch_bounds__(256) void scan2(
    const float* __restrict__ cur,             // [TC][65536]
    float* __restrict__ mem_c, float* __restrict__ msum_c,
    unsigned int* __restrict__ cnt_g,
    int first)
{
    int tid = blockIdx.x * 256 + threadIdx.x;  // 65536 threads
    float mem  = first ? 0.f : mem_c[tid];
    float msum = first ? 0.f : msum_c[tid];
    float s = (!first && mem > 1.f) ? 1.f : 0.f;
    int cnt = 0;
    const float beta = 0.9048374180359595f;    // exp(-1/10)
    const float* base = cur + tid;

    float c[10], n[10];
#pragma unroll
    for (int i = 0; i < 10; ++i) c[i] = base[(size_t)i * 65536];

#pragma unroll
    for (int g = 0; g < 25; ++g) {
        if (g < 24) {
#pragma unroll
            for (int i = 0; i < 10; ++i)
                n[i] = base[(size_t)((g + 1) * 10 + i) * 65536];
        }
#pragma unroll
        for (int i = 0; i < 10; ++i) {
            mem = beta * mem + c[i] - s;
            msum += mem;
            bool b = mem > 1.f;
            s = b ? 1.f : 0.f;
            cnt += (int)b;
        }
#pragma unroll
        for (int i = 0; i < 10; ++i) c[i] = n[i];
    }
    mem_c[tid] = mem;
    msum_c[tid] = msum;
    int rc = cnt;
#pragma unroll
    for (int off = 32; off > 0; off >>= 1) rc += __shfl_down(rc, off);
    if ((threadIdx.x & 63) == 0) atomicAdd(cnt_g, (unsigned int)rc);
}

// out[b,o] = (msum[b,:]/T)@Wr[o,:] + br[o] + (s1sum[b,:]/T)@Ws[o,:] + bs[o]
__global__ __launch_bounds__(256) void readout(
    const float* __restrict__ msum, const float* __restrict__ s1sum,
    const float* __restrict__ Wr, const float* __restrict__ br,
    const float* __restrict__ Ws, const float* __restrict__ bs,
    const unsigned int* __restrict__ cnt1, const unsigned int* __restrict__ cnt2,
    float* __restrict__ out)
{
    __shared__ float r0[256], r1[256];
    int b = blockIdx.x, t = threadIdx.x;
    const float inv_t = 1.0f / 500.0f;
    float m  = msum[b * 256 + t] * inv_t;
    float p0 = m * Wr[t];
    float p1 = m * Wr[256 + t];
    float sa = s1sum[b * 512 + t] * inv_t;
    float sb = s1sum[b * 512 + 256 + t] * inv_t;
    p0 += sa * Ws[t]       + sb * Ws[256 + t];
    p1 += sa * Ws[512 + t] + sb * Ws[768 + t];
    r0[t] = p0; r1[t] = p1;
    __syncthreads();
    for (int st = 128; st > 0; st >>= 1) {
        if (t < st) { r0[t] += r0[t + st]; r1[t] += r1[t + st]; }
        __syncthreads();
    }
    if (t == 0) {
        out[b * 2 + 0] = r0[0] + br[0] + bs[0];
        out[b * 2 + 1] = r1[0] + br[1] + bs[1];
        if (b == 0) {
            out[512] = (float)cnt1[0] * (1.0f / 65536000.0f);
            out[513] = (float)cnt2[0] * (1.0f / 32768000.0f);
        }
    }
}

extern "C" void kernel_launch(void* const* d_in, const int* in_sizes, int n_in,
                              void* d_out, int out_size, void* d_ws, size_t ws_size,
                              hipStream_t stream) {
    const float* spikes = (const float*)d_in[0];
    const float* W1 = (const float*)d_in[1];
    const float* b1 = (const float*)d_in[2];
    const float* W2 = (const float*)d_in[3];
    const float* b2 = (const float*)d_in[4];
    const float* Wr = (const float*)d_in[5];
    const float* br = (const float*)d_in[6];
    const float* Ws = (const float*)d_in[7];
    const float* bs = (const float*)d_in[8];
    float* out = (float*)d_out;

    char* wsb = (char*)d_ws;
    size_t o = 0;
    unsigned short* w1s = (unsigned short*)(wsb + o); o += (size_t)2 * 65536 * 2;     // 256 KB
    unsigned short* w2s = (unsigned short*)(wsb + o); o += (size_t)2 * 131072 * 2;    // 512 KB
    float* cur1 = (float*)(wsb + o);                  o += (size_t)TC * 131072 * 4;   // 131 MB
    float* cur2 = (float*)(wsb + o);                  o += (size_t)TC * 65536 * 4;    // 65.5 MB
    unsigned long long* spkb = (unsigned long long*)(wsb + o); o += (size_t)TC * 2048 * 8; // 4.1 MB
    float* mem1  = (float*)(wsb + o); o += 524288;
    float* s1sum = (float*)(wsb + o); o += 524288;
    float* mem2  = (float*)(wsb + o); o += 262144;
    float* msum  = (float*)(wsb + o); o += 262144;
    unsigned int* cnt1 = (unsigned int*)(wsb + o); o += 256;
    unsigned int* cnt2 = (unsigned int*)(wsb + o); o += 256;

    prep_weights<<<512, 256, 0, stream>>>(W1, W2, w1s, w2s, cnt1, cnt2);

    const int M = TC * BATCH;   // 64000 rows per chunk
    for (int c = 0; c < NCHUNK; ++c) {
        const float* Ac = spikes + (size_t)c * TC * BATCH * NIN;
        gemm1_fused<<<dim3(M / 128, NH1 / 128), 256, 0, stream>>>(Ac, w1s, b1, cur1, M);
        scan1<<<512, 256, 0, stream>>>(cur1, spkb, mem1, s1sum, cnt1, c == 0);
        gemm2<<<dim3(M / 128, NH2 / 128), 256, 0, stream>>>(
            (const unsigned char*)spkb, w2s, b2, cur2, M);
        scan2<<<256, 256, 0, stream>>>(cur2, mem2, msum, cnt2, c == 0);
    }

    readout<<<256, 256, 0, stream>>>(msum, s1sum, Wr, br, Ws, bs, cnt1, cnt2, out);
}